// Round 16
// baseline (96.541 us; speedup 1.0000x reference)
//
#include <hip/hip_runtime.h>
#include <hip/hip_bf16.h>

// Problem constants (Atten_tit): B=16, T=256, K=256, H=512, A=49
#define B_ 16
#define T_ 256
#define K_ 256
#define H_ 512
#define A_ 49
#define APAD 64
#define GRID2 512
#define XPAD 520   // ushort stride (+8 pad)

typedef __attribute__((ext_vector_type(8))) short short8;   // bf16x8
typedef __attribute__((ext_vector_type(4))) float f32x4;

__device__ __forceinline__ ushort f2bf(float f) {
    uint u = __builtin_bit_cast(uint, f);
    u += 0x7FFF + ((u >> 16) & 1);   // RNE
    return (ushort)(u >> 16);
}

// split f32 -> bf16 hi + bf16 lo (residual); hi+lo ~ 17 mantissa bits.
__device__ __forceinline__ void cvt_hilo(float4 v0, float4 v1, short8& hi, short8& lo) {
    float v[8] = {v0.x, v0.y, v0.z, v0.w, v1.x, v1.y, v1.z, v1.w};
    #pragma unroll
    for (int i = 0; i < 8; ++i) {
        ushort h = f2bf(v[i]);
        float hf = __builtin_bit_cast(float, (uint)h << 16);
        hi[i] = (short)h;
        lo[i] = (short)f2bf(v[i] - hf);
    }
}

// 1/(exp(2x)+1); tanh(x) = 1 - 2*sig2(x). exp saturation handles extremes.
__device__ __forceinline__ float sig2(float x) {
    float e = __expf(2.f * x);
    return __builtin_amdgcn_rcpf(e + 1.f);
}

// ---------------------------------------------------------------------------
// kPre: blocks [0,128): Wv,Wg -> Whl[m][hl][64][512] bf16 hi/lo (rows>=49 zero)
//       blocks [128,2176): transpose des (B,K,H) f32 -> desT (B,H,K) bf16.
// Both independent; memory-bound; fills the machine.
__global__ __launch_bounds__(256) void kPre(const float* __restrict__ des,
                                            const float* __restrict__ Wv,
                                            const float* __restrict__ Wg,
                                            ushort* __restrict__ Whl,
                                            ushort* __restrict__ desT)
{
    __shared__ float Tls[32][33];
    int tid = threadIdx.x;

    if (blockIdx.x < 128) {
        // ---- W conversion ----
        int blk = blockIdx.x;              // m = blk>>6, row = blk&63
        int m = blk >> 6, row = blk & 63;
        const float* W = m ? Wg : Wv;
        ushort* hi = Whl + ((size_t)(m * 2 + 0) * 64 + row) * H_;
        ushort* lo = Whl + ((size_t)(m * 2 + 1) * 64 + row) * H_;
        #pragma unroll
        for (int c = tid; c < H_; c += 256) {
            float v = (row < A_) ? W[(size_t)row * H_ + c] : 0.f;
            ushort h = f2bf(v);
            float hf = __builtin_bit_cast(float, (uint)h << 16);
            hi[c] = h;
            lo[c] = f2bf(v - hf);
        }
        return;
    }

    // ---- transpose (round-7 proven) ----
    int tb = blockIdx.x - 128;            // b(16) x kt(8) x ht(16)
    int b = tb >> 7, rem = tb & 127;
    int k0 = (rem >> 4) * 32, h0 = (rem & 15) * 32;
    int kk = tid >> 3, c4 = (tid & 7) * 4;
    float4 v = *(const float4*)(des + ((size_t)(b * K_ + k0 + kk) * H_) + h0 + c4);
    Tls[kk][c4 + 0] = v.x; Tls[kk][c4 + 1] = v.y;
    Tls[kk][c4 + 2] = v.z; Tls[kk][c4 + 3] = v.w;
    __syncthreads();
    int hh = tid >> 3;
    ushort4 o;
    o.x = f2bf(Tls[c4 + 0][hh]);
    o.y = f2bf(Tls[c4 + 1][hh]);
    o.z = f2bf(Tls[c4 + 2][hh]);
    o.w = f2bf(Tls[c4 + 3][hh]);
    *(ushort4*)(desT + ((size_t)(b * H_ + h0 + hh) * K_) + k0 + c4) = o;
}

// ---------------------------------------------------------------------------
// kMain: 512 blocks x 512 threads, __launch_bounds__(512,4) -> VGPR<=128,
// LDS 33.3 KB -> 2 blocks/CU guaranteed co-resident (barrier-safe).
// Block bid: b = bid&15 (XCD b%8 for BOTH P0 writes and P1 reads), j = bid>>4.
// P0 (proj, R13 structure): j<16: des tile (b, k-rows j*16..) -> cvT (B,64,K);
//   j>=16: title tile (b, t-rows (j-16)*16..) -> cg (B*T,64). X staged hi/lo
//   in LDS by all 512 threads; waves 0-3 compute (1 a-group each, 3 MFMA/step).
// Grid barrier (agent-scope atomic; counter memset'd per launch).
// P1 (kZ, R15 TT=8 structure, R13 sig2 numerics): t0 = j*8.
union U2 {
    struct { ushort xhi[16][XPAD]; ushort xlo[16][XPAD]; } p;          // 33280 B
    struct { float cg[8][APAD]; float wh[APAD];
             float rm[8][4]; float rs[8][4]; ushort a[16][K_ + 8]; } z; // 11008 B
};

__global__ __launch_bounds__(512, 4) void kMain(const float* __restrict__ des,
                                                const float* __restrict__ title,
                                                const ushort* __restrict__ Whl,
                                                const float* __restrict__ Wh,
                                                const ushort* __restrict__ desT,
                                                float* __restrict__ cvT,
                                                float* __restrict__ cg,
                                                float* __restrict__ alpha,
                                                float* __restrict__ chat,
                                                uint* __restrict__ counter)
{
    __shared__ U2 u;
    int tid = threadIdx.x;
    int bid = blockIdx.x;
    int b = bid & 15;
    int j = bid >> 4;                     // 0..31
    bool isDes = j < 16;

    // ================= P0: projection =================
    const float* Xbase = isDes ? (des + ((size_t)(b * K_ + j * 16)) * H_)
                               : (title + ((size_t)(b * T_ + (j - 16) * 16)) * H_);
    {   // stage X tile (16x512) hi/lo: 8192 els, 16/thread, coalesced
        #pragma unroll
        for (int it = 0; it < 2; ++it) {
            int eidx = it * 4096 + tid * 8;
            int r = eidx >> 9, c = eidx & 511;
            const float* p = Xbase + (size_t)r * H_ + c;
            float4 v0 = *(const float4*)(p);
            float4 v1 = *(const float4*)(p + 4);
            short8 hi, lo;
            cvt_hilo(v0, v1, hi, lo);
            *(short8*)&u.p.xhi[r][c] = hi;
            *(short8*)&u.p.xlo[r][c] = lo;
        }
    }
    __syncthreads();

    int wv = tid >> 6, lane = tid & 63;
    int lr = lane & 15, lc = lane >> 4;

    if (wv < 4) {
        int g = wv;                       // a-group 0..3
        int m = isDes ? 0 : 1;
        const ushort* whiP = Whl + ((size_t)(m * 2 + 0) * 64 + g * 16 + lr) * H_ + lc * 8;
        const ushort* wloP = Whl + ((size_t)(m * 2 + 1) * 64 + g * 16 + lr) * H_ + lc * 8;

        f32x4 acc = {};
        #pragma unroll 4
        for (int k0 = 0; k0 < H_; k0 += 32) {
            short8 whi = *(const short8*)(whiP + k0);
            short8 wlo = *(const short8*)(wloP + k0);
            short8 xhi = *(const short8*)&u.p.xhi[lr][k0 + lc * 8];
            short8 xlo = *(const short8*)&u.p.xlo[lr][k0 + lc * 8];
            if (isDes) {   // A = W (rows=a), B = X (cols = k-row)
                acc = __builtin_amdgcn_mfma_f32_16x16x32_bf16(whi, xhi, acc, 0, 0, 0);
                acc = __builtin_amdgcn_mfma_f32_16x16x32_bf16(whi, xlo, acc, 0, 0, 0);
                acc = __builtin_amdgcn_mfma_f32_16x16x32_bf16(wlo, xhi, acc, 0, 0, 0);
            } else {       // A = X (rows=t), B = W (cols=a)
                acc = __builtin_amdgcn_mfma_f32_16x16x32_bf16(xhi, whi, acc, 0, 0, 0);
                acc = __builtin_amdgcn_mfma_f32_16x16x32_bf16(xlo, whi, acc, 0, 0, 0);
                acc = __builtin_amdgcn_mfma_f32_16x16x32_bf16(xhi, wlo, acc, 0, 0, 0);
            }
        }

        if (isDes) {
            int kb = j * 16;
            #pragma unroll
            for (int r = 0; r < 4; ++r) {
                int a = g * 16 + lc * 4 + r;           // C row = a
                cvT[((size_t)b * APAD + a) * K_ + kb + lr] = acc[r];
            }
        } else {
            int trows = b * T_ + (j - 16) * 16;        // global title row
            #pragma unroll
            for (int r = 0; r < 4; ++r) {
                int row = trows + lc * 4 + r;          // C row = t
                cg[(size_t)row * APAD + g * 16 + lr] = acc[r];
            }
        }
    }

    // ================= grid barrier =================
    __syncthreads();
    if (tid == 0) {
        __hip_atomic_fetch_add(counter, 1u, __ATOMIC_ACQ_REL, __HIP_MEMORY_SCOPE_AGENT);
        while (__hip_atomic_load(counter, __ATOMIC_ACQUIRE, __HIP_MEMORY_SCOPE_AGENT) < GRID2)
            __builtin_amdgcn_s_sleep(8);
    }
    __syncthreads();

    // ================= P1: z + softmax + PV (TT=8) =================
    int t0 = j * 8;
    int k  = tid & 255;
    int tg = tid >> 8;                    // 0..1
    int tb2 = tg * 4;

    if (tid < 128) {
        int row = tid >> 4, c = (tid & 15) * 4;
        *(float4*)(&u.z.cg[row][c]) =
            *(const float4*)(cg + (size_t)(b * T_ + t0 + row) * APAD + c);
    } else if (tid < 128 + APAD) {
        int a = tid - 128;
        u.z.wh[a] = (a < A_) ? Wh[a] : 0.f;
    }
    {   // zero sA rows 8..15 (PV A-operand has 16 rows; 8 real)
        uint* zp = (uint*)&u.z.a[8][0];   // 8 x 264 ushort = 1056 uint
        #pragma unroll
        for (int i = tid; i < 1056; i += 512) zp[i] = 0;
    }
    __syncthreads();

    // ---- z phase: rolling 8-wide xa loads, 4 t's per thread ----
    const float* cvp = cvT + (size_t)b * APAD * K_ + k;
    float zacc[4] = {0.f, 0.f, 0.f, 0.f};

    for (int c6 = 0; c6 < 6; ++c6) {      // a = 0..47
        int a0 = c6 * 8;
        float xa[8];
        #pragma unroll
        for (int i = 0; i < 8; ++i) xa[i] = cvp[(size_t)(a0 + i) * K_];
        float4 w0 = *(const float4*)&u.z.wh[a0];
        float4 w1 = *(const float4*)&u.z.wh[a0 + 4];
        #pragma unroll
        for (int jj = 0; jj < 4; ++jj) {
            float4 c0 = *(const float4*)&u.z.cg[tb2 + jj][a0];
            float4 c1 = *(const float4*)&u.z.cg[tb2 + jj][a0 + 4];
            zacc[jj] += w0.x * sig2(xa[0] + c0.x) + w0.y * sig2(xa[1] + c0.y)
                      + w0.z * sig2(xa[2] + c0.z) + w0.w * sig2(xa[3] + c0.w)
                      + w1.x * sig2(xa[4] + c1.x) + w1.y * sig2(xa[5] + c1.y)
                      + w1.z * sig2(xa[6] + c1.z) + w1.w * sig2(xa[7] + c1.w);
        }
    }
    {   // tail a = 48
        float xa48 = cvp[(size_t)48 * K_];
        float wh = u.z.wh[48];
        #pragma unroll
        for (int jj = 0; jj < 4; ++jj)
            zacc[jj] += wh * sig2(xa48 + u.z.cg[tb2 + jj][48]);
    }
    float sw = 0.f;
    #pragma unroll
    for (int q = 0; q < 16; ++q) {
        float4 w4 = *(const float4*)&u.z.wh[q * 4];
        sw += w4.x + w4.y + w4.z + w4.w;
    }
    float z[4];
    #pragma unroll
    for (int jj = 0; jj < 4; ++jj) z[jj] = sw - 2.f * zacc[jj];

    // ---- softmax over k (4 waves per tg group) ----
    int w3 = wv & 3;
    #pragma unroll
    for (int jj = 0; jj < 4; ++jj) {
        float mx = z[jj];
        #pragma unroll
        for (int off = 32; off > 0; off >>= 1) mx = fmaxf(mx, __shfl_xor(mx, off));
        if (lane == 0) u.z.rm[tb2 + jj][w3] = mx;
    }
    __syncthreads();
    #pragma unroll
    for (int jj = 0; jj < 4; ++jj) {
        int t = tb2 + jj;
        float mx = fmaxf(fmaxf(u.z.rm[t][0], u.z.rm[t][1]),
                         fmaxf(u.z.rm[t][2], u.z.rm[t][3]));
        z[jj] = __expf(z[jj] - mx);
    }
    #pragma unroll
    for (int jj = 0; jj < 4; ++jj) {
        float s = z[jj];
        #pragma unroll
        for (int off = 32; off > 0; off >>= 1) s += __shfl_xor(s, off);
        if (lane == 0) u.z.rs[tb2 + jj][w3] = s;
    }
    __syncthreads();
    #pragma unroll
    for (int jj = 0; jj < 4; ++jj) {
        int t = tb2 + jj;
        float s = u.z.rs[t][0] + u.z.rs[t][1] + u.z.rs[t][2] + u.z.rs[t][3];
        float rs = __builtin_amdgcn_rcpf(s);
        rs = rs * (2.f - s * rs);              // Newton step
        float al = z[jj] * rs;
        alpha[(size_t)(b * T_ + t0 + t) * K_ + k] = al;
        u.z.a[t][k] = f2bf(al);
    }
    __syncthreads();

    // ---- PV: wave wv -> h-panel [wv*64, +64), per-j 4-deep B loads ----
    int h0 = wv * 64;
    const ushort* Bp = desT + ((size_t)(b * H_ + h0 + lr)) * K_ + lc * 8;

    short8 af[8];
    #pragma unroll
    for (int s = 0; s < 8; ++s)
        af[s] = *(const short8*)(&u.z.a[lr][s * 32 + lc * 8]);

    f32x4 acc[4] = {};
    #pragma unroll
    for (int jj = 0; jj < 4; ++jj) {
        const ushort* Bj = Bp + (size_t)(jj * 16) * K_;
        short8 bf[8];
        #pragma unroll
        for (int s = 0; s < 8; ++s)
            bf[s] = *(const short8*)(Bj + s * 32);
        #pragma unroll
        for (int s = 0; s < 8; ++s)
            acc[jj] = __builtin_amdgcn_mfma_f32_16x16x32_bf16(af[s], bf[s], acc[jj], 0, 0, 0);
    }

    #pragma unroll
    for (int jj = 0; jj < 4; ++jj) {
        #pragma unroll
        for (int r = 0; r < 4; ++r) {
            int row = lc * 4 + r;
            if (row < 8)
                chat[((size_t)(b * T_ + t0 + row)) * H_ + h0 + jj * 16 + lr] = acc[jj][r];
        }
    }
}

// ---------------------------------------------------------------------------
extern "C" void kernel_launch(void* const* d_in, const int* in_sizes, int n_in,
                              void* d_out, int out_size, void* d_ws, size_t ws_size,
                              hipStream_t stream) {
    const float* des   = (const float*)d_in[0];
    const float* title = (const float*)d_in[1];
    const float* Wv    = (const float*)d_in[2];
    const float* Wg    = (const float*)d_in[3];
    const float* Wh    = (const float*)d_in[4];

    float* chat  = (float*)d_out;                            // (B,T,H)
    float* alpha = (float*)d_out + (size_t)B_ * T_ * H_;     // (B,T,K)

    char* ws = (char*)d_ws;
    float*  cvT  = (float*)ws;                               // (B,64,K) f32: 1 MB
    float*  cg   = cvT + (size_t)B_ * APAD * K_;             // (B*T,64) f32: 1 MB
    ushort* desT = (ushort*)(cg + (size_t)B_ * T_ * APAD);   // (B,H,K) bf16: 4 MB
    ushort* Whl  = desT + (size_t)B_ * H_ * K_;              // [2][2][64][512]: 256 KB
    uint* counter = (uint*)(Whl + (size_t)4 * 64 * H_);      // barrier counter

    hipMemsetAsync(counter, 0, 128, stream);                 // graph-safe reset
    hipLaunchKernelGGL(kPre, dim3(2176), dim3(256), 0, stream,
                       des, Wv, Wg, Whl, desT);
    hipLaunchKernelGGL(kMain, dim3(GRID2), dim3(512), 0, stream,
                       des, title, Whl, Wh, desT, cvT, cg, alpha, chat, counter);
}

// Round 17
// 52.820 us; speedup vs baseline: 1.8277x; 1.8277x over previous
//
#include <hip/hip_runtime.h>
#include <hip/hip_bf16.h>

// Problem constants (Atten_tit): B=16, T=256, K=256, H=512, A=49
#define B_ 16
#define T_ 256
#define K_ 256
#define H_ 512
#define A_ 49
#define APAD 64

typedef __attribute__((ext_vector_type(8))) short short8;   // bf16x8
typedef __attribute__((ext_vector_type(4))) float f32x4;

__device__ __forceinline__ ushort f2bf(float f) {
    uint u = __builtin_bit_cast(uint, f);
    u += 0x7FFF + ((u >> 16) & 1);   // RNE
    return (ushort)(u >> 16);
}

// split f32 -> bf16 hi + bf16 lo (residual); hi+lo ~ 17 mantissa bits.
__device__ __forceinline__ void cvt_hilo(float4 v0, float4 v1, short8& hi, short8& lo) {
    float v[8] = {v0.x, v0.y, v0.z, v0.w, v1.x, v1.y, v1.z, v1.w};
    #pragma unroll
    for (int i = 0; i < 8; ++i) {
        ushort h = f2bf(v[i]);
        float hf = __builtin_bit_cast(float, (uint)h << 16);
        hi[i] = (short)h;
        lo[i] = (short)f2bf(v[i] - hf);
    }
}

// 1/(exp(2x)+1); tanh(x) = 1 - 2*sig2(x). exp saturation handles extremes.
__device__ __forceinline__ float sig2(float x) {
    float e = __expf(2.f * x);
    return __builtin_amdgcn_rcpf(e + 1.f);
}

// ---------------------------------------------------------------------------
// kW: Wv,Wg (49x512 f32) -> Whl[m][hl][64][512] bf16, rows >=49 zeroed.
__global__ __launch_bounds__(256) void kW(const float* __restrict__ Wv,
                                          const float* __restrict__ Wg,
                                          ushort* __restrict__ Whl)
{
    int blk = blockIdx.x;              // 0..127: m = blk>>6, row = blk&63
    int m = blk >> 6, row = blk & 63;
    const float* W = m ? Wg : Wv;
    int tid = threadIdx.x;
    ushort* hi = Whl + ((size_t)(m * 2 + 0) * 64 + row) * H_;
    ushort* lo = Whl + ((size_t)(m * 2 + 1) * 64 + row) * H_;
    #pragma unroll
    for (int c = tid; c < H_; c += 256) {
        float v = (row < A_) ? W[(size_t)row * H_ + c] : 0.f;
        ushort h = f2bf(v);
        float hf = __builtin_bit_cast(float, (uint)h << 16);
        hi[c] = h;
        lo[c] = f2bf(v - hf);
    }
}

// ---------------------------------------------------------------------------
// kAP (R13 proj, transpose pass ELIMINATED): 512 blocks. X tile (16x512)
//   converted to hi/lo bf16 in LDS once per block (coalesced, 32 el/thread).
//   des blocks ALSO emit desT (B,H,K) bf16 straight from the staged xhi --
//   the transpose falls out of the staging for free (no extra global reads).
//   k-loop per wave: {2 W loads (L2-resident Whl), 2 LDS b128, 3 MFMA}.
//     tiles 0..255   (des):   C = W x des-rows -> cvT (B,64,K), + desT write
//     tiles 256..511 (title): C = title-rows x W -> cg (B*T,64)
#define XPAD 520   // ushort stride (+8): rows 4 banks apart -> 2-way, free
struct UAP { ushort xhi[16][XPAD]; ushort xlo[16][XPAD]; };   // 33280 B

__global__ __launch_bounds__(256) void kAP(const float* __restrict__ des,
                                           const float* __restrict__ title,
                                           const ushort* __restrict__ Whl,
                                           float* __restrict__ cvT,
                                           float* __restrict__ cg,
                                           ushort* __restrict__ desT)
{
    __shared__ UAP u;
    int tid = threadIdx.x;

    int tile = blockIdx.x;                    // 0..511
    bool isDes = tile < 256;
    const float* Xbase = isDes ? (des + (size_t)tile * 16 * H_)
                               : (title + (size_t)(tile - 256) * 16 * H_);

    {   // stage X tile as hi/lo bf16: 8192 els, 32/thread, coalesced
        #pragma unroll
        for (int it = 0; it < 4; ++it) {
            int eidx = it * 2048 + tid * 8;
            int r = eidx >> 9, c = eidx & 511;
            const float* p = Xbase + (size_t)r * H_ + c;
            float4 v0 = *(const float4*)(p);
            float4 v1 = *(const float4*)(p + 4);
            short8 hi, lo;
            cvt_hilo(v0, v1, hi, lo);
            *(short8*)&u.xhi[r][c] = hi;
            *(short8*)&u.xlo[r][c] = lo;
        }
    }
    __syncthreads();

    // ---- des blocks: emit desT[b][h][krows..+16] from staged xhi ----
    // (bit-identical to the old transpose pass: both are f2bf(des).)
    if (isDes) {
        int krows = tile * 16;
        int bb = krows >> 8, kb = krows & 255;
        #pragma unroll
        for (int hh = 0; hh < 2; ++hh) {
            int h = tid + hh * 256;           // 0..511
            ushort tmp[16];
            #pragma unroll
            for (int i = 0; i < 16; ++i) tmp[i] = u.xhi[i][h];  // 2-way banks
            ushort* dst = desT + ((size_t)(bb * H_ + h)) * K_ + kb;
            *(uint4*)(dst)     = *(uint4*)&tmp[0];
            *(uint4*)(dst + 8) = *(uint4*)&tmp[8];
        }
    }

    int wv = tid >> 6, lane = tid & 63;
    int lr = lane & 15, lc = lane >> 4;
    int g = wv;                               // a-group 0..3
    int m = isDes ? 0 : 1;
    const ushort* whiP = Whl + ((size_t)(m * 2 + 0) * 64 + g * 16 + lr) * H_ + lc * 8;
    const ushort* wloP = Whl + ((size_t)(m * 2 + 1) * 64 + g * 16 + lr) * H_ + lc * 8;

    f32x4 acc = {};
    #pragma unroll 4
    for (int k0 = 0; k0 < H_; k0 += 32) {
        short8 whi = *(const short8*)(whiP + k0);
        short8 wlo = *(const short8*)(wloP + k0);
        short8 xhi = *(const short8*)&u.xhi[lr][k0 + lc * 8];
        short8 xlo = *(const short8*)&u.xlo[lr][k0 + lc * 8];
        if (isDes) {     // A = W (rows=a), B = X (cols = k-row of des)
            acc = __builtin_amdgcn_mfma_f32_16x16x32_bf16(whi, xhi, acc, 0, 0, 0);
            acc = __builtin_amdgcn_mfma_f32_16x16x32_bf16(whi, xlo, acc, 0, 0, 0);
            acc = __builtin_amdgcn_mfma_f32_16x16x32_bf16(wlo, xhi, acc, 0, 0, 0);
        } else {         // A = X (rows=t), B = W (cols=a)
            acc = __builtin_amdgcn_mfma_f32_16x16x32_bf16(xhi, whi, acc, 0, 0, 0);
            acc = __builtin_amdgcn_mfma_f32_16x16x32_bf16(xlo, whi, acc, 0, 0, 0);
            acc = __builtin_amdgcn_mfma_f32_16x16x32_bf16(xhi, wlo, acc, 0, 0, 0);
        }
    }

    if (isDes) {
        int krows = tile * 16;
        int b = krows >> 8, kb = krows & 255;
        #pragma unroll
        for (int r = 0; r < 4; ++r) {
            int a = g * 16 + lc * 4 + r;           // C row = a
            cvT[((size_t)b * APAD + a) * K_ + kb + lr] = acc[r];
        }
    } else {
        int trows = (tile - 256) * 16;             // global title row (b*T+t)
        #pragma unroll
        for (int r = 0; r < 4; ++r) {
            int row = trows + lc * 4 + r;          // C row = t
            cg[(size_t)row * APAD + g * 16 + lr] = acc[r];
        }
    }
}

// ---------------------------------------------------------------------------
// kZ (R13 exact): fused z + softmax + PV. 512 blocks x 512 threads (TT=8).
// b = bid&15 (XCD-homed; FETCH 3 MB verified R11). Thread (k=tid&255,
// tg=tid>>8) owns t = tg*4 + {0..3}. Rolling 8-wide xa loads.
// PV: 8 waves x 64-h panels, per-j 4-deep B loads.
__global__ __launch_bounds__(512) void kZ(const float* __restrict__ cvT,
                                          const float* __restrict__ cg,
                                          const float* __restrict__ Wh,
                                          const ushort* __restrict__ desT,
                                          float* __restrict__ alpha,
                                          float* __restrict__ chat)
{
    __shared__ float  sCg[8][APAD];        // 2 KB
    __shared__ float  sWh[APAD];
    __shared__ float  sRedM[8][4];
    __shared__ float  sRedS[8][4];
    __shared__ ushort sA[16][K_ + 8];      // 8.4 KB

    int bid = blockIdx.x;                 // 512 blocks
    int b  = bid & 15;
    int t0 = (bid >> 4) * 8;
    int tid = threadIdx.x;
    int k  = tid & 255;
    int tg = tid >> 8;                    // 0..1
    int tb = tg * 4;

    if (tid < 128) {
        int row = tid >> 4, c = (tid & 15) * 4;
        *(float4*)(&sCg[row][c]) =
            *(const float4*)(cg + (size_t)(b * T_ + t0 + row) * APAD + c);
    } else if (tid < 128 + APAD) {
        int a = tid - 128;
        sWh[a] = (a < A_) ? Wh[a] : 0.f;
    }
    {   // zero sA rows 8..15 (PV A-operand has 16 rows; 8 real)
        uint* zp = (uint*)&sA[8][0];      // 8 x 264 ushort = 1056 uint
        #pragma unroll
        for (int i = tid; i < 1056; i += 512) zp[i] = 0;
    }
    __syncthreads();

    // ---- z phase: rolling 8-wide xa loads, 4 t's per thread ----
    const float* cvp = cvT + (size_t)b * APAD * K_ + k;
    float zacc[4] = {0.f, 0.f, 0.f, 0.f};

    for (int c6 = 0; c6 < 6; ++c6) {      // a = 0..47
        int a0 = c6 * 8;
        float xa[8];
        #pragma unroll
        for (int i = 0; i < 8; ++i) xa[i] = cvp[(size_t)(a0 + i) * K_];
        float4 w0 = *(const float4*)&sWh[a0];
        float4 w1 = *(const float4*)&sWh[a0 + 4];
        #pragma unroll
        for (int j = 0; j < 4; ++j) {
            float4 c0 = *(const float4*)&sCg[tb + j][a0];
            float4 c1 = *(const float4*)&sCg[tb + j][a0 + 4];
            zacc[j] += w0.x * sig2(xa[0] + c0.x) + w0.y * sig2(xa[1] + c0.y)
                     + w0.z * sig2(xa[2] + c0.z) + w0.w * sig2(xa[3] + c0.w)
                     + w1.x * sig2(xa[4] + c1.x) + w1.y * sig2(xa[5] + c1.y)
                     + w1.z * sig2(xa[6] + c1.z) + w1.w * sig2(xa[7] + c1.w);
        }
    }
    {   // tail a = 48
        float xa48 = cvp[(size_t)48 * K_];
        float wh = sWh[48];
        #pragma unroll
        for (int j = 0; j < 4; ++j)
            zacc[j] += wh * sig2(xa48 + sCg[tb + j][48]);
    }
    float sw = 0.f;
    #pragma unroll
    for (int q = 0; q < 16; ++q) {
        float4 w4 = *(const float4*)&sWh[q * 4];
        sw += w4.x + w4.y + w4.z + w4.w;
    }
    float z[4];
    #pragma unroll
    for (int j = 0; j < 4; ++j) z[j] = sw - 2.f * zacc[j];

    // ---- softmax over k (4 waves per tg group) ----
    int wv = tid >> 6, lane = tid & 63, w3 = wv & 3;
    #pragma unroll
    for (int j = 0; j < 4; ++j) {
        float m = z[j];
        #pragma unroll
        for (int off = 32; off > 0; off >>= 1) m = fmaxf(m, __shfl_xor(m, off));
        if (lane == 0) sRedM[tb + j][w3] = m;
    }
    __syncthreads();
    #pragma unroll
    for (int j = 0; j < 4; ++j) {
        int t = tb + j;
        float m = fmaxf(fmaxf(sRedM[t][0], sRedM[t][1]),
                        fmaxf(sRedM[t][2], sRedM[t][3]));
        z[j] = __expf(z[j] - m);
    }
    #pragma unroll
    for (int j = 0; j < 4; ++j) {
        float s = z[j];
        #pragma unroll
        for (int off = 32; off > 0; off >>= 1) s += __shfl_xor(s, off);
        if (lane == 0) sRedS[tb + j][w3] = s;
    }
    __syncthreads();
    #pragma unroll
    for (int j = 0; j < 4; ++j) {
        int t = tb + j;
        float s = sRedS[t][0] + sRedS[t][1] + sRedS[t][2] + sRedS[t][3];
        float rs = __builtin_amdgcn_rcpf(s);
        rs = rs * (2.f - s * rs);              // Newton step
        float al = z[j] * rs;
        alpha[(size_t)(b * T_ + t0 + t) * K_ + k] = al;
        sA[t][k] = f2bf(al);
    }
    __syncthreads();

    // ---- PV: wave wv -> h-panel [wv*64, +64), per-j 4-deep B loads ----
    int lr = lane & 15, lc = lane >> 4;
    int h0 = wv * 64;
    const ushort* Bp = desT + ((size_t)(b * H_ + h0 + lr)) * K_ + lc * 8;

    short8 af[8];
    #pragma unroll
    for (int s = 0; s < 8; ++s)
        af[s] = *(const short8*)(&sA[lr][s * 32 + lc * 8]);

    f32x4 acc[4] = {};
    #pragma unroll
    for (int j = 0; j < 4; ++j) {
        const ushort* Bj = Bp + (size_t)(j * 16) * K_;
        short8 bf[8];
        #pragma unroll
        for (int s = 0; s < 8; ++s)
            bf[s] = *(const short8*)(Bj + s * 32);
        #pragma unroll
        for (int s = 0; s < 8; ++s)
            acc[j] = __builtin_amdgcn_mfma_f32_16x16x32_bf16(af[s], bf[s], acc[j], 0, 0, 0);
    }

    #pragma unroll
    for (int j = 0; j < 4; ++j) {
        #pragma unroll
        for (int r = 0; r < 4; ++r) {
            int row = lc * 4 + r;
            if (row < 8)
                chat[((size_t)(b * T_ + t0 + row)) * H_ + h0 + j * 16 + lr] = acc[j][r];
        }
    }
}

// ---------------------------------------------------------------------------
extern "C" void kernel_launch(void* const* d_in, const int* in_sizes, int n_in,
                              void* d_out, int out_size, void* d_ws, size_t ws_size,
                              hipStream_t stream) {
    const float* des   = (const float*)d_in[0];
    const float* title = (const float*)d_in[1];
    const float* Wv    = (const float*)d_in[2];
    const float* Wg    = (const float*)d_in[3];
    const float* Wh    = (const float*)d_in[4];

    float* chat  = (float*)d_out;                            // (B,T,H)
    float* alpha = (float*)d_out + (size_t)B_ * T_ * H_;     // (B,T,K)

    char* ws = (char*)d_ws;
    float*  cvT  = (float*)ws;                               // (B,64,K) f32: 1 MB
    float*  cg   = cvT + (size_t)B_ * APAD * K_;             // (B*T,64) f32: 1 MB
    ushort* desT = (ushort*)(cg + (size_t)B_ * T_ * APAD);   // (B,H,K) bf16: 4 MB
    ushort* Whl  = desT + (size_t)B_ * H_ * K_;              // [2][2][64][512]: 256 KB

    hipLaunchKernelGGL(kW, dim3(128), dim3(256), 0, stream, Wv, Wg, Whl);
    hipLaunchKernelGGL(kAP, dim3(512), dim3(256), 0, stream,
                       des, title, Whl, cvT, cg, desT);
    hipLaunchKernelGGL(kZ, dim3(2 * B_ * (T_ / 16)), dim3(512), 0, stream,
                       cvT, cg, Wh, desT, alpha, chat);
}